// Round 1
// baseline (272.794 us; speedup 1.0000x reference)
//
#include <hip/hip_runtime.h>

#define DEV static __device__ __forceinline__

typedef __attribute__((ext_vector_type(8))) short short8;
typedef __attribute__((ext_vector_type(4))) float f32x4;

DEV unsigned short f2bf(float f) {
    union { float f; unsigned int u; } v; v.f = f;
    unsigned int u = v.u;
    unsigned int r = (u + 0x7fffu + ((u >> 16) & 1u)) >> 16;
    return (unsigned short)r;
}

// ---------------- kernel 0: fp32 weights -> bf16 ----------------
__global__ void prep_kernel(const float* __restrict__ qkv_w,
                            const float* __restrict__ proj_w,
                            unsigned short* __restrict__ Wq,
                            unsigned short* __restrict__ Wp) {
    int i = blockIdx.x * blockDim.x + threadIdx.x;
    int stride = gridDim.x * blockDim.x;
    for (int j = i; j < 1536 * 512; j += stride) Wq[j] = f2bf(qkv_w[j]);
    for (int j = i; j < 512 * 512;  j += stride) Wp[j] = f2bf(proj_w[j]);
}

// ---------------- kernel 1: x [b][512][2048] f32 -> Xt [b][2048][512] bf16
__global__ __launch_bounds__(256) void transpose_kernel(const float* __restrict__ x,
                                                        unsigned short* __restrict__ Xt) {
    __shared__ unsigned char lt[64 * 128];  // 64 c-rows x 64 t bf16, XOR-swizzled
    int b  = blockIdx.z;
    int c0 = blockIdx.y * 64;
    int t0 = blockIdx.x * 64;
    int tid = threadIdx.x;
    // phase 1: coalesced float4 reads along t, b64 swizzled LDS writes
    int tx = tid & 15, cy0 = tid >> 4;
    for (int p = 0; p < 4; ++p) {
        int cy = cy0 + p * 16;
        const float* src = &x[((size_t)(b * 512 + c0 + cy)) * 2048 + t0 + tx * 4];
        f32x4 v = *(const f32x4*)src;
        unsigned long long pk = (unsigned long long)f2bf(v[0])
                              | ((unsigned long long)f2bf(v[1]) << 16)
                              | ((unsigned long long)f2bf(v[2]) << 32)
                              | ((unsigned long long)f2bf(v[3]) << 48);
        int addr = (cy * 128 + tx * 8) ^ ((cy & 7) << 4);
        *(unsigned long long*)(lt + addr) = pk;
    }
    __syncthreads();
    // phase 2: gather 16 c per thread, 32B coalesced global writes
    int c16 = (tid & 3) * 16, tr = tid >> 2;
    unsigned short buf[16];
    for (int i = 0; i < 16; ++i) {
        int c = c16 + i;
        int addr = (c * 128 + tr * 2) ^ ((c & 7) << 4);
        buf[i] = *(unsigned short*)(lt + addr);
    }
    unsigned short* dst = &Xt[((size_t)(b * 2048 + t0 + tr)) * 512 + c0 + c16];
    *(short8*)dst       = *(short8*)&buf[0];
    *(short8*)(dst + 8) = *(short8*)&buf[8];
}

// ---------------- kernel 2: QKV GEMM ----------------
// ORIENT 0: D[t][o] (Q/K tiles, o-tile 0..7)  -> Qw/Kw [bh][T][ch]
// ORIENT 1: D[o][t] (V tiles,  o-tile 8..11)  -> Vw    [bh][ch][T]
#define LP 72  // 64 + 8 pad (keeps ds_read_b128 16B-aligned, ~2-way banks)

template <int ORIENT>
__global__ __launch_bounds__(256, 2) void gemm_qkv_kernel(
    const unsigned short* __restrict__ Wq,   // [1536][512] bf16
    const unsigned short* __restrict__ Xt,   // [b][2048][512] bf16
    const float* __restrict__ qkv_b,
    unsigned short* __restrict__ Qw,
    unsigned short* __restrict__ Kw,
    unsigned short* __restrict__ Vw) {
    __shared__ unsigned short Ws[128][LP];   // [o][k]
    __shared__ unsigned short Bs[128][LP];   // [t][k]
    int b  = blockIdx.z;
    int ot = (ORIENT == 0) ? blockIdx.y : (8 + blockIdx.y);
    int o0 = ot * 128, t0 = blockIdx.x * 128;
    int tid = threadIdx.x, lane = tid & 63, w = tid >> 6;
    int lr = lane >> 4, lc = lane & 15;
    int wr = (w >> 1) * 64, wc = (w & 1) * 64;
    f32x4 acc[4][4];
    for (int m = 0; m < 4; m++)
        for (int n = 0; n < 4; n++) acc[m][n] = (f32x4){0.f, 0.f, 0.f, 0.f};
    int srow = tid >> 3, soff = (tid & 7) * 8;
    for (int k0 = 0; k0 < 512; k0 += 64) {
        __syncthreads();
        for (int rr = srow; rr < 128; rr += 32) {
            *(short8*)&Ws[rr][soff] = *(const short8*)&Wq[(size_t)(o0 + rr) * 512 + k0 + soff];
            *(short8*)&Bs[rr][soff] = *(const short8*)&Xt[((size_t)(b * 2048) + t0 + rr) * 512 + k0 + soff];
        }
        __syncthreads();
        for (int kk = 0; kk < 64; kk += 32) {
            int kb = kk + lr * 8;
            short8 af[4], bfv[4];
            if (ORIENT == 0) {
                for (int m = 0; m < 4; m++) af[m]  = *(const short8*)&Bs[wr + m * 16 + lc][kb];
                for (int n = 0; n < 4; n++) bfv[n] = *(const short8*)&Ws[wc + n * 16 + lc][kb];
            } else {
                for (int m = 0; m < 4; m++) af[m]  = *(const short8*)&Ws[wr + m * 16 + lc][kb];
                for (int n = 0; n < 4; n++) bfv[n] = *(const short8*)&Bs[wc + n * 16 + lc][kb];
            }
            for (int m = 0; m < 4; m++)
                for (int n = 0; n < 4; n++)
                    acc[m][n] = __builtin_amdgcn_mfma_f32_16x16x32_bf16(af[m], bfv[n], acc[m][n], 0, 0, 0);
        }
    }
    const float scale = 0.29730177875068026f;  // 128^-0.25
    for (int m = 0; m < 4; m++)
        for (int n = 0; n < 4; n++)
            for (int r = 0; r < 4; r++) {
                int row = wr + m * 16 + lr * 4 + r;
                int col = wc + n * 16 + lc;
                float val = acc[m][n][r];
                if (ORIENT == 0) {
                    int t = t0 + row;
                    int o = o0 + col;
                    val = (val + qkv_b[o]) * scale;
                    if (o < 512) {
                        int h = o >> 7, cc = o & 127;
                        Qw[((size_t)((b * 4 + h) * 2048 + t)) * 128 + cc] = f2bf(val);
                    } else {
                        int oo = o - 512;
                        int h = oo >> 7, cc = oo & 127;
                        Kw[((size_t)((b * 4 + h) * 2048 + t)) * 128 + cc] = f2bf(val);
                    }
                } else {
                    int o = o0 + row;
                    int t = t0 + col;
                    val += qkv_b[o];
                    int oo = o - 1024;
                    int h = oo >> 7, cc = oo & 127;
                    Vw[((size_t)((b * 4 + h) * 128 + cc)) * 2048 + t] = f2bf(val);
                }
            }
}

// ---------------- kernel 3: flash attention ----------------
// block: 128 q-rows of one bh; 4 waves x 32 q-rows; KV tiles of 64
__global__ __launch_bounds__(256, 2) void attn_kernel(
    const unsigned short* __restrict__ Qw,   // [bh][2048][128]
    const unsigned short* __restrict__ Kw,   // [bh][2048][128]
    const unsigned short* __restrict__ Vw,   // [bh][128][2048]
    unsigned short* __restrict__ Aw) {       // [b][2048][512]
    __shared__ unsigned short Ks[64][136];   // [s][ch]
    __shared__ unsigned short Vs[128][72];   // [c][s]
    __shared__ unsigned short Ps[128][72];   // [q][s]
    int bh = blockIdx.y;
    int t0 = blockIdx.x * 128;
    int tid = threadIdx.x, lane = tid & 63, w = tid >> 6;
    int lr = lane >> 4, lc = lane & 15;
    // Q fragments resident in registers: rows w*32 + m*16 + lc, k = kk*32 + lr*8
    short8 qf[2][4];
    for (int m = 0; m < 2; m++)
        for (int kk = 0; kk < 4; kk++)
            qf[m][kk] = *(const short8*)&Qw[((size_t)(bh * 2048) + t0 + w * 32 + m * 16 + lc) * 128 + kk * 32 + lr * 8];
    f32x4 oacc[2][8];
    for (int m = 0; m < 2; m++)
        for (int n = 0; n < 8; n++) oacc[m][n] = (f32x4){0.f, 0.f, 0.f, 0.f};
    float mst[2][4], lst[2][4];
    for (int m = 0; m < 2; m++)
        for (int r = 0; r < 4; r++) { mst[m][r] = -1e30f; lst[m][r] = 0.f; }

    for (int s0 = 0; s0 < 2048; s0 += 64) {
        __syncthreads();
        {   // stage K tile [64][128] and V tile [128][64]
            int kr = tid >> 4, koff = (tid & 15) * 8;
            for (int rr = kr; rr < 64; rr += 16)
                *(short8*)&Ks[rr][koff] = *(const short8*)&Kw[((size_t)(bh * 2048) + s0 + rr) * 128 + koff];
            int vr = tid >> 3, voff = (tid & 7) * 8;
            for (int rr = vr; rr < 128; rr += 32)
                *(short8*)&Vs[rr][voff] = *(const short8*)&Vw[((size_t)(bh * 128) + rr) * 2048 + s0 + voff];
        }
        __syncthreads();
        // S = Q K^T  (D rows = q, cols = s)
        f32x4 sacc[2][4];
        for (int m = 0; m < 2; m++)
            for (int n = 0; n < 4; n++) sacc[m][n] = (f32x4){0.f, 0.f, 0.f, 0.f};
        for (int kk = 0; kk < 4; kk++) {
            short8 kf[4];
            for (int n = 0; n < 4; n++) kf[n] = *(const short8*)&Ks[n * 16 + lc][kk * 32 + lr * 8];
            for (int m = 0; m < 2; m++)
                for (int n = 0; n < 4; n++)
                    sacc[m][n] = __builtin_amdgcn_mfma_f32_16x16x32_bf16(qf[m][kk], kf[n], sacc[m][n], 0, 0, 0);
        }
        // online softmax, wave-parallel (16-lane row groups)
        for (int m = 0; m < 2; m++)
            for (int r = 0; r < 4; r++) {
                float mx = fmaxf(fmaxf(sacc[m][0][r], sacc[m][1][r]),
                                 fmaxf(sacc[m][2][r], sacc[m][3][r]));
                for (int d = 1; d < 16; d <<= 1) mx = fmaxf(mx, __shfl_xor(mx, d, 64));
                float mnew = fmaxf(mst[m][r], mx);
                float resc = __expf(mst[m][r] - mnew);
                mst[m][r] = mnew;
                float rs = 0.f;
                for (int n = 0; n < 4; n++) {
                    float p0 = __expf(sacc[m][n][r] - mnew);
                    sacc[m][n][r] = p0;
                    rs += p0;
                }
                for (int d = 1; d < 16; d <<= 1) rs += __shfl_xor(rs, d, 64);
                lst[m][r] = lst[m][r] * resc + rs;
                for (int n = 0; n < 8; n++) oacc[m][n][r] *= resc;
            }
        // P -> LDS (bf16); same-wave rows only, DS ops in-order per wave
        for (int m = 0; m < 2; m++)
            for (int n = 0; n < 4; n++)
                for (int r = 0; r < 4; r++)
                    Ps[w * 32 + m * 16 + lr * 4 + r][n * 16 + lc] = f2bf(sacc[m][n][r]);
        asm volatile("" ::: "memory");
        // O += P V^T  (A = P [q][s], B from Vs [c][s])
        for (int kk = 0; kk < 2; kk++) {
            short8 pa[2], vb[8];
            for (int m = 0; m < 2; m++) pa[m] = *(const short8*)&Ps[w * 32 + m * 16 + lc][kk * 32 + lr * 8];
            for (int n = 0; n < 8; n++) vb[n] = *(const short8*)&Vs[n * 16 + lc][kk * 32 + lr * 8];
            for (int m = 0; m < 2; m++)
                for (int n = 0; n < 8; n++)
                    oacc[m][n] = __builtin_amdgcn_mfma_f32_16x16x32_bf16(pa[m], vb[n], oacc[m][n], 0, 0, 0);
        }
    }
    // epilogue: O / l -> Aw[b][t][h*128+c]
    int b = bh >> 2, h = bh & 3;
    for (int m = 0; m < 2; m++) {
        float inv[4];
        for (int r = 0; r < 4; r++) inv[r] = 1.f / lst[m][r];
        for (int n = 0; n < 8; n++)
            for (int r = 0; r < 4; r++) {
                int t = t0 + w * 32 + m * 16 + lr * 4 + r;
                int c = h * 128 + n * 16 + lc;
                Aw[((size_t)(b * 2048) + t) * 512 + c] = f2bf(oacc[m][n][r] * inv[r]);
            }
    }
}

// ---------------- kernel 4: proj GEMM + bias + residual ----------------
__global__ __launch_bounds__(256, 2) void gemm_proj_kernel(
    const unsigned short* __restrict__ Wp,   // [512][512] bf16
    const unsigned short* __restrict__ Aw,   // [b][2048][512] bf16
    const float* __restrict__ proj_b,
    const float* __restrict__ x,             // [b][512][2048] f32
    float* __restrict__ out) {
    __shared__ unsigned short Ws[128][LP];   // [o][k]
    __shared__ unsigned short Bs[128][LP];   // [t][k]
    int b  = blockIdx.z;
    int o0 = blockIdx.y * 128, t0 = blockIdx.x * 128;
    int tid = threadIdx.x, lane = tid & 63, w = tid >> 6;
    int lr = lane >> 4, lc = lane & 15;
    int wr = (w >> 1) * 64, wc = (w & 1) * 64;
    f32x4 acc[4][4];
    for (int m = 0; m < 4; m++)
        for (int n = 0; n < 4; n++) acc[m][n] = (f32x4){0.f, 0.f, 0.f, 0.f};
    int srow = tid >> 3, soff = (tid & 7) * 8;
    for (int k0 = 0; k0 < 512; k0 += 64) {
        __syncthreads();
        for (int rr = srow; rr < 128; rr += 32) {
            *(short8*)&Ws[rr][soff] = *(const short8*)&Wp[(size_t)(o0 + rr) * 512 + k0 + soff];
            *(short8*)&Bs[rr][soff] = *(const short8*)&Aw[((size_t)(b * 2048) + t0 + rr) * 512 + k0 + soff];
        }
        __syncthreads();
        for (int kk = 0; kk < 64; kk += 32) {
            int kb = kk + lr * 8;
            short8 af[4], bfv[4];
            for (int m = 0; m < 4; m++) af[m]  = *(const short8*)&Ws[wr + m * 16 + lc][kb];
            for (int n = 0; n < 4; n++) bfv[n] = *(const short8*)&Bs[wc + n * 16 + lc][kb];
            for (int m = 0; m < 4; m++)
                for (int n = 0; n < 4; n++)
                    acc[m][n] = __builtin_amdgcn_mfma_f32_16x16x32_bf16(af[m], bfv[n], acc[m][n], 0, 0, 0);
        }
    }
    // D[m=o][n=t]; out = x + h + bias (residual in fp32, exact)
    for (int m = 0; m < 4; m++)
        for (int n = 0; n < 4; n++)
            for (int r = 0; r < 4; r++) {
                int o = o0 + wr + m * 16 + lr * 4 + r;
                int t = t0 + wc + n * 16 + lc;
                size_t idx = ((size_t)(b * 512) + o) * 2048 + t;
                out[idx] = x[idx] + acc[m][n][r] + proj_b[o];
            }
}

extern "C" void kernel_launch(void* const* d_in, const int* in_sizes, int n_in,
                              void* d_out, int out_size, void* d_ws, size_t ws_size,
                              hipStream_t stream) {
    const float* x      = (const float*)d_in[0];
    const float* qkv_w  = (const float*)d_in[1];
    const float* qkv_b  = (const float*)d_in[2];
    const float* proj_w = (const float*)d_in[3];
    const float* proj_b = (const float*)d_in[4];
    float* out = (float*)d_out;

    unsigned short* ws = (unsigned short*)d_ws;
    unsigned short* Wq = ws;                                   // 1536*512
    unsigned short* Wp = Wq + (size_t)1536 * 512;              // 512*512
    unsigned short* Xt = Wp + (size_t)512 * 512;               // 8*2048*512
    unsigned short* Qw = Xt + (size_t)8 * 2048 * 512;          // 32*2048*128
    unsigned short* Kw = Qw + (size_t)32 * 2048 * 128;
    unsigned short* Vw = Kw + (size_t)32 * 2048 * 128;
    unsigned short* Aw = Vw + (size_t)32 * 2048 * 128;         // 8*2048*512

    prep_kernel<<<dim3(512), dim3(256), 0, stream>>>(qkv_w, proj_w, Wq, Wp);
    transpose_kernel<<<dim3(32, 8, 8), dim3(256), 0, stream>>>(x, Xt);
    gemm_qkv_kernel<0><<<dim3(16, 8, 8), dim3(256), 0, stream>>>(Wq, Xt, qkv_b, Qw, Kw, Vw);
    gemm_qkv_kernel<1><<<dim3(16, 4, 8), dim3(256), 0, stream>>>(Wq, Xt, qkv_b, Qw, Kw, Vw);
    attn_kernel<<<dim3(16, 32), dim3(256), 0, stream>>>(Qw, Kw, Vw, Aw);
    gemm_proj_kernel<<<dim3(16, 4, 8), dim3(256), 0, stream>>>(Wp, Aw, proj_b, x, out);
}